// Round 11
// baseline (171.978 us; speedup 1.0000x reference)
//
#include <hip/hip_runtime.h>

#define TSEQ 2048
#define DM   2048
#define NHEAD 16

typedef __bf16 bf16x8 __attribute__((ext_vector_type(8)));
typedef float  f32x4  __attribute__((ext_vector_type(4)));
typedef unsigned short ushort8v __attribute__((ext_vector_type(8)));
typedef unsigned int u32x4v __attribute__((ext_vector_type(4)));
typedef const __attribute__((address_space(1))) void* gas_cvp;
typedef __attribute__((address_space(3))) void* las_vp;

__device__ __forceinline__ unsigned short f2bf(float f) {
  unsigned int u = __builtin_bit_cast(unsigned int, f);
  u += 0x7FFFu + ((u >> 16) & 1u);
  return (unsigned short)(u >> 16);
}

// ---------------- fused fp32 -> bf16 conversion (5 tensors, 1 launch) ------
__global__ __launch_bounds__(256) void cvt5(const float* __restrict__ x,
                                            const float* __restrict__ wq,
                                            const float* __restrict__ wk,
                                            const float* __restrict__ wv,
                                            const float* __restrict__ wp,
                                            unsigned short* __restrict__ xb,
                                            unsigned short* __restrict__ wqkvb,
                                            unsigned short* __restrict__ wpb) {
  const int NEL = DM * TSEQ;
  int gid = blockIdx.x * 256 + threadIdx.x;
  int seg = gid >> 19;
  int i = gid & ((1 << 19) - 1);
  const float* src;
  unsigned short* dst;
  switch (seg) {
    case 0: src = x;  dst = xb;                      break;
    case 1: src = wq; dst = wqkvb;                   break;
    case 2: src = wk; dst = wqkvb + (size_t)NEL;     break;
    case 3: src = wv; dst = wqkvb + (size_t)2 * NEL; break;
    default: src = wp; dst = wpb;                    break;
  }
  const float4* p = (const float4*)src + (size_t)i * 2;
  float4 a = p[0], b = p[1];
  ushort8v o;
  o[0] = f2bf(a.x); o[1] = f2bf(a.y); o[2] = f2bf(a.z); o[3] = f2bf(a.w);
  o[4] = f2bf(b.x); o[5] = f2bf(b.y); o[6] = f2bf(b.z); o[7] = f2bf(b.w);
  *((ushort8v*)dst + i) = o;
}

// ---------------- QKV GEMM: C[2048][6144] = A x B^T --------------------------
// BM=256 BN=192, grid 256 = 1 block/CU. 512 threads, 8 waves (4M x 2N).
__global__ __launch_bounds__(512, 2) void gemm_qkv(const unsigned short* __restrict__ A,
                                                   const unsigned short* __restrict__ B,
                                                   float* __restrict__ C) {
  constexpr int TB = (256 + 192) * 128;   // 57344 B per buffer
  __shared__ char lds[2 * TB];

  int orig = blockIdx.x;
  int swz = (orig & 7) * 32 + (orig >> 3);
  int bx = swz & 31, by = swz >> 5;
  int tileM = by * 256, tileN = bx * 192;

  int tid = threadIdx.x, w = tid >> 6, lane = tid & 63;
  int l15 = lane & 15, l4 = lane >> 4;
  int wm = w >> 1, wn = w & 1;
  int xorsw = (l15 & 7) << 4;
  int srow = tid >> 3, scolb = (tid & 7) * 16;

  const char* Ag = (const char*)A;
  const char* Bg = (const char*)B;

  f32x4 acc[4][6] = {};

  auto stage = [&](int kt, int bsel) {
    char* dst0 = lds + bsel * TB + srow * 128 + scolb;
    #pragma unroll
    for (int i = 0; i < 7; ++i) {
      int row = i * 64 + srow;
      const char* src = (row < 256 ? Ag + (size_t)(tileM + row) * 4096
                                   : Bg + (size_t)(tileN + row - 256) * 4096)
                        + kt * 128 + (scolb ^ ((row & 7) << 4));
      __builtin_amdgcn_global_load_lds((gas_cvp)src, (las_vp)(dst0 + i * 8192), 16, 0, 0);
    }
  };

  stage(0, 0);
  #pragma unroll 2
  for (int t = 0; t < 32; ++t) {
    int buf = t & 1;
    asm volatile("s_waitcnt vmcnt(0)" ::: "memory");
    __builtin_amdgcn_s_barrier();
    asm volatile("" ::: "memory");
    if (t + 1 < 32) stage(t + 1, buf ^ 1);
    __builtin_amdgcn_sched_barrier(0);

    const char* Lb = lds + buf * TB;
    bf16x8 a[4][2], b[6][2];
    #pragma unroll
    for (int mf = 0; mf < 4; ++mf)
      #pragma unroll
      for (int kk = 0; kk < 2; ++kk)
        a[mf][kk] = *(const bf16x8*)(Lb + (wm * 64 + mf * 16 + l15) * 128 + ((kk * 64 + l4 * 16) ^ xorsw));
    #pragma unroll
    for (int nf = 0; nf < 6; ++nf)
      #pragma unroll
      for (int kk = 0; kk < 2; ++kk)
        b[nf][kk] = *(const bf16x8*)(Lb + 32768 + (wn * 96 + nf * 16 + l15) * 128 + ((kk * 64 + l4 * 16) ^ xorsw));
    #pragma unroll
    for (int kk = 0; kk < 2; ++kk)
      #pragma unroll
      for (int mf = 0; mf < 4; ++mf)
        #pragma unroll
        for (int nf = 0; nf < 6; ++nf)
          acc[mf][nf] = __builtin_amdgcn_mfma_f32_16x16x32_bf16(a[mf][kk], b[nf][kk], acc[mf][nf], 0, 0, 0);
  }

  #pragma unroll
  for (int mf = 0; mf < 4; ++mf) {
    int r0 = tileM + wm * 64 + mf * 16 + l4 * 4;
    #pragma unroll
    for (int nf = 0; nf < 6; ++nf) {
      int c0 = tileN + wn * 96 + nf * 16 + l15;
      #pragma unroll
      for (int j = 0; j < 4; ++j)
        C[(size_t)(r0 + j) * 6144 + c0] = acc[mf][nf][j];
    }
  }
}

// ---------------- proj GEMM: C[2048][2048] = A x B^T -------------------------
__global__ __launch_bounds__(512, 2) void gemm_proj(const unsigned short* __restrict__ A,
                                                    const unsigned short* __restrict__ B,
                                                    float* __restrict__ C) {
  constexpr int TB = 256 * 128;
  __shared__ char lds[3 * TB];

  int orig = blockIdx.x;
  int swz = (orig & 7) * 32 + (orig >> 3);
  int bx = swz & 15, by = swz >> 4;
  int tileM = by * 128, tileN = bx * 128;

  int tid = threadIdx.x, w = tid >> 6, lane = tid & 63;
  int l15 = lane & 15, l4 = lane >> 4;
  int wm = w >> 2, wn = (w >> 1) & 1, ks = w & 1;
  int xorsw = (l15 & 7) << 4;
  int srow = tid >> 3, scolb = (tid & 7) * 16;
  int kb = ks * 64;

  const char* Ag = (const char*)A;
  const char* Bg = (const char*)B;

  f32x4 acc[4][4] = {};

  auto stage = [&](int kt, int bsel) {
    char* dst0 = lds + bsel * TB + srow * 128 + scolb;
    #pragma unroll
    for (int i = 0; i < 4; ++i) {
      int row = i * 64 + srow;
      const char* src = (row < 128 ? Ag + (size_t)(tileM + row) * 4096
                                   : Bg + (size_t)(tileN + row - 128) * 4096)
                        + kt * 128 + (scolb ^ ((row & 7) << 4));
      __builtin_amdgcn_global_load_lds((gas_cvp)src, (las_vp)(dst0 + i * 8192), 16, 0, 0);
    }
  };

  stage(0, 0);
  stage(1, 1);
  #pragma unroll 3
  for (int t = 0; t < 32; ++t) {
    int buf = t % 3;
    if (t + 1 < 32) { asm volatile("s_waitcnt vmcnt(4)" ::: "memory"); }
    else            { asm volatile("s_waitcnt vmcnt(0)" ::: "memory"); }
    __builtin_amdgcn_s_barrier();
    __builtin_amdgcn_sched_barrier(0);
    if (t + 2 < 32) stage(t + 2, (t + 2) % 3);

    const char* Lb = lds + buf * TB;
    bf16x8 a[4], b[4];
    #pragma unroll
    for (int mf = 0; mf < 4; ++mf)
      a[mf] = *(const bf16x8*)(Lb + (wm * 64 + mf * 16 + l15) * 128 + ((kb + l4 * 16) ^ xorsw));
    #pragma unroll
    for (int nf = 0; nf < 4; ++nf)
      b[nf] = *(const bf16x8*)(Lb + (128 + wn * 64 + nf * 16 + l15) * 128 + ((kb + l4 * 16) ^ xorsw));
    #pragma unroll
    for (int mf = 0; mf < 4; ++mf)
      #pragma unroll
      for (int nf = 0; nf < 4; ++nf)
        acc[mf][nf] = __builtin_amdgcn_mfma_f32_16x16x32_bf16(a[mf], b[nf], acc[mf][nf], 0, 0, 0);
  }

  __syncthreads();
  int pair = w >> 1;
  if (ks == 1) {
    #pragma unroll
    for (int mf = 0; mf < 4; ++mf)
      #pragma unroll
      for (int nf = 0; nf < 4; ++nf)
        *(f32x4*)(lds + pair * 16384 + ((mf * 4 + nf) * 64 + lane) * 16) = acc[mf][nf];
  }
  __syncthreads();
  if (ks == 0) {
    #pragma unroll
    for (int mf = 0; mf < 4; ++mf) {
      int r0 = tileM + wm * 64 + mf * 16 + l4 * 4;
      #pragma unroll
      for (int nf = 0; nf < 4; ++nf) {
        f32x4 o = acc[mf][nf] + *(const f32x4*)(lds + pair * 16384 + ((mf * 4 + nf) * 64 + lane) * 16);
        int c0 = tileN + wn * 64 + nf * 16 + l15;
        #pragma unroll
        for (int j = 0; j < 4; ++j)
          C[(size_t)(r0 + j) * 2048 + c0] = o[j];
      }
    }
  }
}

// ---------------- v-mix + RMSNorm + RoPE (one wave per (t,h)) -------------
__global__ __launch_bounds__(256) void qkv_post(const float* __restrict__ qkv,
                                                const float* __restrict__ vi,
                                                const float* __restrict__ lam,
                                                unsigned short* __restrict__ qb,
                                                unsigned short* __restrict__ kb,
                                                unsigned short* __restrict__ vb) {
  int wid = blockIdx.x * 4 + (threadIdx.x >> 6);
  int lane = threadIdx.x & 63;
  int t = wid >> 4, h = wid & 15;
  const float* base = qkv + (size_t)t * (3 * DM) + h * 128;
  float l0 = lam[0], l1 = lam[1];

  float invf = exp2f((float)lane * -0.20762050593046014f);
  float ang = (float)t * invf;
  float sn, cs;
  sincosf(ang, &sn, &cs);

  size_t ob = (size_t)t * DM + h * 128;
  {
    float a = base[lane], b = base[lane + 64];
    float ss = a * a + b * b;
    #pragma unroll
    for (int m = 1; m < 64; m <<= 1) ss += __shfl_xor(ss, m, 64);
    float sc = rsqrtf(ss * (1.0f / 128.0f) + 1.1920929e-07f);
    a *= sc; b *= sc;
    qb[ob + lane]      = f2bf(a * cs + b * sn);
    qb[ob + 64 + lane] = f2bf(b * cs - a * sn);
  }
  {
    float a = base[2048 + lane], b = base[2048 + 64 + lane];
    float ss = a * a + b * b;
    #pragma unroll
    for (int m = 1; m < 64; m <<= 1) ss += __shfl_xor(ss, m, 64);
    float sc = rsqrtf(ss * (1.0f / 128.0f) + 1.1920929e-07f);
    a *= sc; b *= sc;
    kb[ob + lane]      = f2bf(a * cs + b * sn);
    kb[ob + 64 + lane] = f2bf(b * cs - a * sn);
  }
  {
    const float* vib = vi + (size_t)t * DM + h * 128;
    vb[ob + lane]      = f2bf(l0 * base[4096 + lane]      + l1 * vib[lane]);
    vb[ob + 64 + lane] = f2bf(l0 * base[4096 + 64 + lane] + l1 * vib[lane + 64]);
  }
}

// ---------------- V transpose: vb[t][h*128+d] -> vbT[h][d][t] -------------
__global__ __launch_bounds__(256) void transpose_v(const unsigned short* __restrict__ vb,
                                                   unsigned short* __restrict__ vbT) {
  __shared__ __align__(16) unsigned short tile[64][68];
  int t0 = blockIdx.x * 64, d0 = blockIdx.y * 64, h = blockIdx.z;
  int tid = threadIdx.x;
  int li = tid >> 4;
  int lj = (tid & 15) * 4;
  #pragma unroll
  for (int p = 0; p < 4; ++p) {
    int i = p * 16 + li;
    ushort4 v = *(const ushort4*)(vb + (size_t)(t0 + i) * DM + h * 128 + d0 + lj);
    tile[i][lj] = v.x; tile[i][lj + 1] = v.y; tile[i][lj + 2] = v.z; tile[i][lj + 3] = v.w;
  }
  __syncthreads();
  #pragma unroll
  for (int p = 0; p < 4; ++p) {
    int j = p * 16 + li;
    ushort4 wv;
    wv.x = tile[lj][j]; wv.y = tile[lj + 1][j]; wv.z = tile[lj + 2][j]; wv.w = tile[lj + 3][j];
    *(ushort4*)(vbT + (size_t)h * 128 * TSEQ + (size_t)(d0 + j) * TSEQ + t0 + lj) = wv;
  }
}

// ---------------- split-KV causal flash attention (swapped QK^T) ----------
// grid 512, 512 threads (8 waves). bi -> qblk = 7-(bi>>6), h = (bi>>2)&15,
// s = bi&3. QBLK=256 (wave w owns rows qblk*256+w*32), 4 kv-splits of
// exactly (qblk+1) steps each. K,V double-buffered (64KB -> 2 blk/CU,
// 16 waves/CU). cvt_pk bf16 pack + defer-max rescale (THR=8).
__global__ __launch_bounds__(512, 2) void attn_split(const unsigned short* __restrict__ qb,
                                                     const unsigned short* __restrict__ kb,
                                                     const unsigned short* __restrict__ vbT,
                                                     float* __restrict__ O01,
                                                     float* __restrict__ O23,
                                                     float2* __restrict__ ml) {
  __shared__ __align__(16) char Ks[2][16384];
  __shared__ __align__(16) char Vs[2][16384];

  int bi = blockIdx.x;
  int qblk = 7 - (bi >> 6);
  int h = (bi >> 2) & 15;
  int s = bi & 3;
  int len = qblk + 1;                 // steps per split
  int st0 = s * len, st1 = st0 + len;

  int tid = threadIdx.x, w = tid >> 6, lane = tid & 63;
  int l15 = lane & 15, l4 = lane >> 4;
  int qr0 = qblk * 256 + w * 32;
  int xorK = (l15 & 7) << 4;
  int srcA = ((((l4 << 1)) & 3) * 16 + l15) << 2;
  int srcB = ((((l4 << 1) + 1) & 3) * 16 + l15) << 2;
  bool hi4 = (l4 >> 1) != 0;

  bf16x8 q_frag[2][4];
  #pragma unroll
  for (int qt = 0; qt < 2; ++qt) {
    const unsigned short* qrow = qb + (size_t)(qr0 + qt * 16 + l15) * DM + h * 128 + l4 * 8;
    #pragma unroll
    for (int kk = 0; kk < 4; ++kk) q_frag[qt][kk] = *(const bf16x8*)(qrow + kk * 32);
  }

  const char* kbase = (const char*)kb + (size_t)h * 256;
  const char* vbase = (const char*)vbT + (size_t)h * 128 * TSEQ * 2;

  f32x4 acc_o[2][8] = {};
  float mrow[2] = {-1e30f, -1e30f};
  float lrow[2] = {0.f, 0.f};
  const float scale = 0.08838834764831845f;

  auto stage = [&](int st, int bsel) {
    const char* kb1 = kbase + (size_t)st * 64 * 4096;
    const char* vb1 = vbase + (size_t)st * 64 * 2;
    #pragma unroll
    for (int it = 0; it < 2; ++it) {
      int L = (it * 512 + tid) * 16;
      int row = L >> 8, b = L & 255;
      const char* src = kb1 + (size_t)row * 4096 + (b ^ ((row & 7) << 4));
      __builtin_amdgcn_global_load_lds((gas_cvp)src, (las_vp)(&Ks[bsel][0] + L), 16, 0, 0);
    }
    #pragma unroll
    for (int it = 0; it < 2; ++it) {
      int L = (it * 512 + tid) * 16;
      int row = L >> 7, b = L & 127;
      const char* src = vb1 + (size_t)row * (TSEQ * 2) + (b ^ ((row & 7) << 4));
      __builtin_amdgcn_global_load_lds((gas_cvp)src, (las_vp)(&Vs[bsel][0] + L), 16, 0, 0);
    }
  };

  stage(st0, 0);
  int buf = 0;

  for (int st = st0; st < st1; ++st) {
    asm volatile("s_waitcnt vmcnt(0) lgkmcnt(0)" ::: "memory");
    __builtin_amdgcn_s_barrier();
    __builtin_amdgcn_sched_barrier(0);
    if (st + 1 < st1) stage(st + 1, buf ^ 1);

    f32x4 acc_s[2][4] = {};
    __builtin_amdgcn_s_setprio(1);
    #pragma unroll
    for (int j = 0; j < 4; ++j) {
      const char* kr = &Ks[buf][0] + (j * 16 + l15) * 256;
      #pragma unroll
      for (int kk = 0; kk < 4; ++kk) {
        bf16x8 kf = *(const bf16x8*)(kr + ((l4 * 16 + kk * 64) ^ xorK));
        acc_s[0][j] = __builtin_amdgcn_mfma_f32_16x16x32_bf16(kf, q_frag[0][kk], acc_s[0][j], 0, 0, 0);
        acc_s[1][j] = __builtin_amdgcn_mfma_f32_16x16x32_bf16(kf, q_frag[1][kk], acc_s[1][j], 0, 0, 0);
      }
    }
    __builtin_amdgcn_s_setprio(0);

    int kv0 = st * 64;
    bool needmask = (kv0 + 63) > qr0;
    u32x4v pf[2][2];

    #pragma unroll
    for (int qt = 0; qt < 2; ++qt) {
      int qg = qr0 + qt * 16 + l15;
      float sv[4][4];
      float pmax = -1e30f;
      if (needmask) {
        #pragma unroll
        for (int j = 0; j < 4; ++j)
          #pragma unroll
          for (int r = 0; r < 4; ++r) {
            float v = acc_s[qt][j][r] * scale;
            if ((kv0 + j * 16 + l4 * 4 + r) > qg) v = -1e30f;
            sv[j][r] = v;
            pmax = fmaxf(pmax, v);
          }
      } else {
        #pragma unroll
        for (int j = 0; j < 4; ++j)
          #pragma unroll
          for (int r = 0; r < 4; ++r) {
            float v = acc_s[qt][j][r] * scale;
            sv[j][r] = v;
            pmax = fmaxf(pmax, v);
          }
      }
      pmax = fmaxf(pmax, __shfl_xor(pmax, 16, 64));
      pmax = fmaxf(pmax, __shfl_xor(pmax, 32, 64));

      // defer-max: skip rescale when max growth <= 8 (wave-uniform)
      if (!__all(pmax - mrow[qt] <= 8.0f)) {
        float mn = fmaxf(mrow[qt], pmax);
        float f = __expf(mrow[qt] - mn);
        mrow[qt] = mn;
        lrow[qt] *= f;
        #pragma unroll
        for (int n = 0; n < 8; ++n) acc_o[qt][n] *= f;
      }
      float mn = mrow[qt];

      float psum = 0.f;
      unsigned pk[4][2];
      #pragma unroll
      for (int j = 0; j < 4; ++j)
        #pragma unroll
        for (int rr = 0; rr < 2; ++rr) {
          float p0 = __expf(sv[j][2 * rr] - mn);
          float p1 = __expf(sv[j][2 * rr + 1] - mn);
          psum += p0 + p1;
          unsigned pkw;
          asm("v_cvt_pk_bf16_f32 %0, %1, %2" : "=v"(pkw) : "v"(p0), "v"(p1));
          pk[j][rr] = pkw;
        }
      psum += __shfl_xor(psum, 16, 64);
      psum += __shfl_xor(psum, 32, 64);
      lrow[qt] += psum;

      #pragma unroll
      for (int kk = 0; kk < 2; ++kk) {
        u32x4v pw;
        #pragma unroll
        for (int w2 = 0; w2 < 4; ++w2) {
          int rr = w2 & 1;
          int src = (w2 < 2) ? srcA : srcB;
          unsigned c0 = (unsigned)__builtin_amdgcn_ds_bpermute(src, (int)pk[2 * kk][rr]);
          unsigned c1 = (unsigned)__builtin_amdgcn_ds_bpermute(src, (int)pk[2 * kk + 1][rr]);
          pw[w2] = hi4 ? c1 : c0;
        }
        pf[qt][kk] = pw;
      }
    }

    __builtin_amdgcn_s_setprio(1);
    #pragma unroll
    for (int kk = 0; kk < 2; ++kk) {
      bf16x8 pb0 = __builtin_bit_cast(bf16x8, pf[0][kk]);
      bf16x8 pb1 = __builtin_bit_cast(bf16x8, pf[1][kk]);
      #pragma unroll
      for (int n = 0; n < 8; ++n) {
        bf16x8 vf = *(const bf16x8*)(&Vs[buf][0] + (n * 16 + l15) * 128 + ((kk * 64 + l4 * 16) ^ xorK));
        acc_o[0][n] = __builtin_amdgcn_mfma_f32_16x16x32_bf16(vf, pb0, acc_o[0][n], 0, 0, 0);
        acc_o[1][n] = __builtin_amdgcn_mfma_f32_16x16x32_bf16(vf, pb1, acc_o[1][n], 0, 0, 0);
      }
    }
    __builtin_amdgcn_s_setprio(0);
    buf ^= 1;
  }

  float* Op = (s < 2 ? O01 + (size_t)s * (TSEQ * DM)
                     : O23 + (size_t)(s - 2) * (TSEQ * DM));
  #pragma unroll
  for (int qt = 0; qt < 2; ++qt) {
    int q = qr0 + qt * 16 + l15;
    #pragma unroll
    for (int n = 0; n < 8; ++n)
      *(f32x4*)(Op + (size_t)q * DM + h * 128 + n * 16 + l4 * 4) = acc_o[qt][n];
    if (l4 == 0)
      ml[(size_t)s * (TSEQ * NHEAD) + (size_t)q * NHEAD + h] = make_float2(mrow[qt], lrow[qt]);
  }
}

// ---------------- combine 4 split-KV partials -> bf16 y ---------------------
__global__ __launch_bounds__(256) void attn_combine(const float* __restrict__ O01,
                                                    const float* __restrict__ O23,
                                                    const float2* __restrict__ ml,
                                                    unsigned short* __restrict__ yb) {
  const int TN = TSEQ * NHEAD;
  int idx = blockIdx.x * 256 + threadIdx.x;
  int rowid = idx >> 5;
  float2 m0 = ml[rowid];
  float2 m1 = ml[TN + rowid];
  float2 m2 = ml[2 * TN + rowid];
  float2 m3 = ml[3 * TN + rowid];
  float m = fmaxf(fmaxf(m0.x, m1.x), fmaxf(m2.x, m3.x));
  float a0 = __expf(m0.x - m), a1 = __expf(m1.x - m);
  float a2 = __expf(m2.x - m), a3 = __expf(m3.x - m);
  float inv = 1.0f / (a0 * m0.y + a1 * m1.y + a2 * m2.y + a3 * m3.y);
  float4 o0 = ((const float4*)O01)[idx];
  float4 o1 = ((const float4*)(O01 + (size_t)TSEQ * DM))[idx];
  float4 o2 = ((const float4*)O23)[idx];
  float4 o3 = ((const float4*)(O23 + (size_t)TSEQ * DM))[idx];
  ushort4 r;
  r.x = f2bf((a0 * o0.x + a1 * o1.x + a2 * o2.x + a3 * o3.x) * inv);
  r.y = f2bf((a0 * o0.y + a1 * o1.y + a2 * o2.y + a3 * o3.y) * inv);
  r.z = f2bf((a0 * o0.z + a1 * o1.z + a2 * o2.z + a3 * o3.z) * inv);
  r.w = f2bf((a0 * o0.w + a1 * o1.w + a2 * o2.w + a3 * o3.w) * inv);
  *(ushort4*)(yb + (size_t)idx * 4) = r;
}

// ---------------------------------------------------------------------------
extern "C" void kernel_launch(void* const* d_in, const int* in_sizes, int n_in,
                              void* d_out, int out_size, void* d_ws, size_t ws_size,
                              hipStream_t stream) {
  const float* x   = (const float*)d_in[0];
  const float* vi  = (const float*)d_in[1];
  const float* wq  = (const float*)d_in[2];
  const float* wk  = (const float*)d_in[3];
  const float* wv  = (const float*)d_in[4];
  const float* wp  = (const float*)d_in[5];
  const float* lam = (const float*)d_in[6];

  const size_t MB = 1024 * 1024;
  const int NEL = DM * TSEQ;
  const int N8  = NEL / 8;
  char* ws = (char*)d_ws;
  unsigned short* xb    = (unsigned short*)(ws);            // dead after gemm_qkv
  unsigned short* wqkvb = (unsigned short*)(ws + 8  * MB);   // dead after gemm_qkv
  unsigned short* wpb   = (unsigned short*)(ws + 32 * MB);   // live until gemm_proj
  float*          qkv32 = (float*)(ws + 40 * MB);            // dead after qkv_post
  float*          O01   = (float*)(ws);                      // reuses xb/wqkvb (32MB)
  float*          O23   = (float*)(ws + 40 * MB);            // reuses qkv32 (32MB)
  float2*         mlbuf = (float2*)(ws + 72 * MB);           // 1MB
  unsigned short* qb2   = (unsigned short*)(ws + 88 * MB);
  unsigned short* kb2   = (unsigned short*)(ws + 96 * MB);
  unsigned short* vb    = (unsigned short*)(ws + 104 * MB);
  unsigned short* vbT   = (unsigned short*)(ws + 112 * MB);
  unsigned short* yb    = (unsigned short*)(ws + 120 * MB);

  cvt5<<<5 * N8 / 256, 256, 0, stream>>>(x, wq, wk, wv, wp, xb, wqkvb, wpb);

  gemm_qkv<<<256, 512, 0, stream>>>(xb, wqkvb, qkv32);

  qkv_post<<<(TSEQ * NHEAD) / 4, 256, 0, stream>>>(qkv32, vi, lam, qb2, kb2, vb);

  transpose_v<<<dim3(TSEQ / 64, 2, NHEAD), 256, 0, stream>>>(vb, vbT);

  attn_split<<<512, 512, 0, stream>>>(qb2, kb2, vbT, O01, O23, mlbuf);
  attn_combine<<<(TSEQ * DM / 4) / 256, 256, 0, stream>>>(O01, O23, mlbuf, yb);

  gemm_proj<<<256, 512, 0, stream>>>(yb, wpb, (float*)d_out);
}

// Round 12
// 171.623 us; speedup vs baseline: 1.0021x; 1.0021x over previous
//
#include <hip/hip_runtime.h>

#define TSEQ 2048
#define DM   2048
#define NHEAD 16

typedef __bf16 bf16x8 __attribute__((ext_vector_type(8)));
typedef float  f32x4  __attribute__((ext_vector_type(4)));
typedef unsigned short ushort8v __attribute__((ext_vector_type(8)));
typedef unsigned int u32x4v __attribute__((ext_vector_type(4)));
typedef const __attribute__((address_space(1))) void* gas_cvp;
typedef __attribute__((address_space(3))) void* las_vp;

__device__ __forceinline__ unsigned short f2bf(float f) {
  unsigned int u = __builtin_bit_cast(unsigned int, f);
  u += 0x7FFFu + ((u >> 16) & 1u);
  return (unsigned short)(u >> 16);
}

// ---------------- fused fp32 -> bf16 conversion (5 tensors, 1 launch) ------
__global__ __launch_bounds__(256) void cvt5(const float* __restrict__ x,
                                            const float* __restrict__ wq,
                                            const float* __restrict__ wk,
                                            const float* __restrict__ wv,
                                            const float* __restrict__ wp,
                                            unsigned short* __restrict__ xb,
                                            unsigned short* __restrict__ wqkvb,
                                            unsigned short* __restrict__ wpb) {
  const int NEL = DM * TSEQ;
  int gid = blockIdx.x * 256 + threadIdx.x;
  int seg = gid >> 19;
  int i = gid & ((1 << 19) - 1);
  const float* src;
  unsigned short* dst;
  switch (seg) {
    case 0: src = x;  dst = xb;                      break;
    case 1: src = wq; dst = wqkvb;                   break;
    case 2: src = wk; dst = wqkvb + (size_t)NEL;     break;
    case 3: src = wv; dst = wqkvb + (size_t)2 * NEL; break;
    default: src = wp; dst = wpb;                    break;
  }
  const float4* p = (const float4*)src + (size_t)i * 2;
  float4 a = p[0], b = p[1];
  ushort8v o;
  o[0] = f2bf(a.x); o[1] = f2bf(a.y); o[2] = f2bf(a.z); o[3] = f2bf(a.w);
  o[4] = f2bf(b.x); o[5] = f2bf(b.y); o[6] = f2bf(b.z); o[7] = f2bf(b.w);
  *((ushort8v*)dst + i) = o;
}

// ---------------- QKV GEMM: C[2048][6144] = A x B^T --------------------------
// BM=256 BN=192, grid 256 = 1 block/CU. 512 threads, 8 waves (4M x 2N).
// Counted-vmcnt schedule (T4): stage split A(4 chunks)/B(3 chunks); per tile:
// vmcnt(3)->bar->readA->stageA(t+1)->vmcnt(4)->bar->readB->stageB(t+1)->MFMA.
// vmcnt never drains to 0 mid-loop; loads span the whole compute phase.
__global__ __launch_bounds__(512, 2) void gemm_qkv(const unsigned short* __restrict__ A,
                                                   const unsigned short* __restrict__ B,
                                                   float* __restrict__ C) {
  constexpr int TB = (256 + 192) * 128;   // 57344 B per buffer
  __shared__ char lds[2 * TB];

  int orig = blockIdx.x;
  int swz = (orig & 7) * 32 + (orig >> 3);
  int bx = swz & 31, by = swz >> 5;
  int tileM = by * 256, tileN = bx * 192;

  int tid = threadIdx.x, w = tid >> 6, lane = tid & 63;
  int l15 = lane & 15, l4 = lane >> 4;
  int wm = w >> 1, wn = w & 1;
  int xorsw = (l15 & 7) << 4;
  int srow = tid >> 3, scolb = (tid & 7) * 16;

  const char* Ag = (const char*)A;
  const char* Bg = (const char*)B;

  f32x4 acc[4][6] = {};

  auto stageA = [&](int kt, int bsel) {
    char* dst0 = lds + bsel * TB + srow * 128 + scolb;
    #pragma unroll
    for (int i = 0; i < 4; ++i) {
      int row = i * 64 + srow;                       // A rows 0..255
      const char* src = Ag + (size_t)(tileM + row) * 4096
                        + kt * 128 + (scolb ^ ((row & 7) << 4));
      __builtin_amdgcn_global_load_lds((gas_cvp)src, (las_vp)(dst0 + i * 8192), 16, 0, 0);
    }
  };
  auto stageB = [&](int kt, int bsel) {
    char* dst0 = lds + bsel * TB + 32768 + srow * 128 + scolb;
    #pragma unroll
    for (int i = 0; i < 3; ++i) {
      int row = i * 64 + srow;                       // B rows 0..191
      const char* src = Bg + (size_t)(tileN + row) * 4096
                        + kt * 128 + (scolb ^ ((row & 7) << 4));
      __builtin_amdgcn_global_load_lds((gas_cvp)src, (las_vp)(dst0 + i * 8192), 16, 0, 0);
    }
  };

  stageA(0, 0);
  stageB(0, 0);
  #pragma unroll 2
  for (int t = 0; t < 32; ++t) {
    int buf = t & 1;
    const char* Lb = lds + buf * TB;
    bool pf = (t + 1 < 32);

    // ---- A-group resident (B's 3 loads may still fly) ----
    asm volatile("s_waitcnt vmcnt(3)" ::: "memory");
    __builtin_amdgcn_s_barrier();
    asm volatile("" ::: "memory");

    bf16x8 a[4][2], b[6][2];
    #pragma unroll
    for (int mf = 0; mf < 4; ++mf)
      #pragma unroll
      for (int kk = 0; kk < 2; ++kk)
        a[mf][kk] = *(const bf16x8*)(Lb + (wm * 64 + mf * 16 + l15) * 128 + ((kk * 64 + l4 * 16) ^ xorsw));
    if (pf) stageA(t + 1, buf ^ 1);

    // ---- B-group resident (next A's 4 loads may still fly) ----
    if (pf) { asm volatile("s_waitcnt vmcnt(4)" ::: "memory"); }
    else    { asm volatile("s_waitcnt vmcnt(0)" ::: "memory"); }
    __builtin_amdgcn_s_barrier();
    asm volatile("" ::: "memory");

    #pragma unroll
    for (int nf = 0; nf < 6; ++nf)
      #pragma unroll
      for (int kk = 0; kk < 2; ++kk)
        b[nf][kk] = *(const bf16x8*)(Lb + 32768 + (wn * 96 + nf * 16 + l15) * 128 + ((kk * 64 + l4 * 16) ^ xorsw));
    if (pf) stageB(t + 1, buf ^ 1);

    __builtin_amdgcn_s_setprio(1);
    #pragma unroll
    for (int kk = 0; kk < 2; ++kk)
      #pragma unroll
      for (int mf = 0; mf < 4; ++mf)
        #pragma unroll
        for (int nf = 0; nf < 6; ++nf)
          acc[mf][nf] = __builtin_amdgcn_mfma_f32_16x16x32_bf16(a[mf][kk], b[nf][kk], acc[mf][nf], 0, 0, 0);
    __builtin_amdgcn_s_setprio(0);
  }

  #pragma unroll
  for (int mf = 0; mf < 4; ++mf) {
    int r0 = tileM + wm * 64 + mf * 16 + l4 * 4;
    #pragma unroll
    for (int nf = 0; nf < 6; ++nf) {
      int c0 = tileN + wn * 96 + nf * 16 + l15;
      #pragma unroll
      for (int j = 0; j < 4; ++j)
        C[(size_t)(r0 + j) * 6144 + c0] = acc[mf][nf][j];
    }
  }
}

// ---------------- proj GEMM: C[2048][2048] = A x B^T -------------------------
__global__ __launch_bounds__(512, 2) void gemm_proj(const unsigned short* __restrict__ A,
                                                    const unsigned short* __restrict__ B,
                                                    float* __restrict__ C) {
  constexpr int TB = 256 * 128;
  __shared__ char lds[3 * TB];

  int orig = blockIdx.x;
  int swz = (orig & 7) * 32 + (orig >> 3);
  int bx = swz & 15, by = swz >> 4;
  int tileM = by * 128, tileN = bx * 128;

  int tid = threadIdx.x, w = tid >> 6, lane = tid & 63;
  int l15 = lane & 15, l4 = lane >> 4;
  int wm = w >> 2, wn = (w >> 1) & 1, ks = w & 1;
  int xorsw = (l15 & 7) << 4;
  int srow = tid >> 3, scolb = (tid & 7) * 16;
  int kb = ks * 64;

  const char* Ag = (const char*)A;
  const char* Bg = (const char*)B;

  f32x4 acc[4][4] = {};

  auto stage = [&](int kt, int bsel) {
    char* dst0 = lds + bsel * TB + srow * 128 + scolb;
    #pragma unroll
    for (int i = 0; i < 4; ++i) {
      int row = i * 64 + srow;
      const char* src = (row < 128 ? Ag + (size_t)(tileM + row) * 4096
                                   : Bg + (size_t)(tileN + row - 128) * 4096)
                        + kt * 128 + (scolb ^ ((row & 7) << 4));
      __builtin_amdgcn_global_load_lds((gas_cvp)src, (las_vp)(dst0 + i * 8192), 16, 0, 0);
    }
  };

  stage(0, 0);
  stage(1, 1);
  #pragma unroll 3
  for (int t = 0; t < 32; ++t) {
    int buf = t % 3;
    if (t + 1 < 32) { asm volatile("s_waitcnt vmcnt(4)" ::: "memory"); }
    else            { asm volatile("s_waitcnt vmcnt(0)" ::: "memory"); }
    __builtin_amdgcn_s_barrier();
    __builtin_amdgcn_sched_barrier(0);
    if (t + 2 < 32) stage(t + 2, (t + 2) % 3);

    const char* Lb = lds + buf * TB;
    bf16x8 a[4], b[4];
    #pragma unroll
    for (int mf = 0; mf < 4; ++mf)
      a[mf] = *(const bf16x8*)(Lb + (wm * 64 + mf * 16 + l15) * 128 + ((kb + l4 * 16) ^ xorsw));
    #pragma unroll
    for (int nf = 0; nf < 4; ++nf)
      b[nf] = *(const bf16x8*)(Lb + (128 + wn * 64 + nf * 16 + l15) * 128 + ((kb + l4 * 16) ^ xorsw));
    #pragma unroll
    for (int mf = 0; mf < 4; ++mf)
      #pragma unroll
      for (int nf = 0; nf < 4; ++nf)
        acc[mf][nf] = __builtin_amdgcn_mfma_f32_16x16x32_bf16(a[mf], b[nf], acc[mf][nf], 0, 0, 0);
  }

  __syncthreads();
  int pair = w >> 1;
  if (ks == 1) {
    #pragma unroll
    for (int mf = 0; mf < 4; ++mf)
      #pragma unroll
      for (int nf = 0; nf < 4; ++nf)
        *(f32x4*)(lds + pair * 16384 + ((mf * 4 + nf) * 64 + lane) * 16) = acc[mf][nf];
  }
  __syncthreads();
  if (ks == 0) {
    #pragma unroll
    for (int mf = 0; mf < 4; ++mf) {
      int r0 = tileM + wm * 64 + mf * 16 + l4 * 4;
      #pragma unroll
      for (int nf = 0; nf < 4; ++nf) {
        f32x4 o = acc[mf][nf] + *(const f32x4*)(lds + pair * 16384 + ((mf * 4 + nf) * 64 + lane) * 16);
        int c0 = tileN + wn * 64 + nf * 16 + l15;
        #pragma unroll
        for (int j = 0; j < 4; ++j)
          C[(size_t)(r0 + j) * 2048 + c0] = o[j];
      }
    }
  }
}

// ---------------- v-mix + RMSNorm + RoPE (one wave per (t,h)) -------------
__global__ __launch_bounds__(256) void qkv_post(const float* __restrict__ qkv,
                                                const float* __restrict__ vi,
                                                const float* __restrict__ lam,
                                                unsigned short* __restrict__ qb,
                                                unsigned short* __restrict__ kb,
                                                unsigned short* __restrict__ vb) {
  int wid = blockIdx.x * 4 + (threadIdx.x >> 6);
  int lane = threadIdx.x & 63;
  int t = wid >> 4, h = wid & 15;
  const float* base = qkv + (size_t)t * (3 * DM) + h * 128;
  float l0 = lam[0], l1 = lam[1];

  float invf = exp2f((float)lane * -0.20762050593046014f);
  float ang = (float)t * invf;
  float sn, cs;
  sincosf(ang, &sn, &cs);

  size_t ob = (size_t)t * DM + h * 128;
  {
    float a = base[lane], b = base[lane + 64];
    float ss = a * a + b * b;
    #pragma unroll
    for (int m = 1; m < 64; m <<= 1) ss += __shfl_xor(ss, m, 64);
    float sc = rsqrtf(ss * (1.0f / 128.0f) + 1.1920929e-07f);
    a *= sc; b *= sc;
    qb[ob + lane]      = f2bf(a * cs + b * sn);
    qb[ob + 64 + lane] = f2bf(b * cs - a * sn);
  }
  {
    float a = base[2048 + lane], b = base[2048 + 64 + lane];
    float ss = a * a + b * b;
    #pragma unroll
    for (int m = 1; m < 64; m <<= 1) ss += __shfl_xor(ss, m, 64);
    float sc = rsqrtf(ss * (1.0f / 128.0f) + 1.1920929e-07f);
    a *= sc; b *= sc;
    kb[ob + lane]      = f2bf(a * cs + b * sn);
    kb[ob + 64 + lane] = f2bf(b * cs - a * sn);
  }
  {
    const float* vib = vi + (size_t)t * DM + h * 128;
    vb[ob + lane]      = f2bf(l0 * base[4096 + lane]      + l1 * vib[lane]);
    vb[ob + 64 + lane] = f2bf(l0 * base[4096 + 64 + lane] + l1 * vib[lane + 64]);
  }
}

// ---------------- V transpose: vb[t][h*128+d] -> vbT[h][d][t] -------------
__global__ __launch_bounds__(256) void transpose_v(const unsigned short* __restrict__ vb,
                                                   unsigned short* __restrict__ vbT) {
  __shared__ __align__(16) unsigned short tile[64][68];
  int t0 = blockIdx.x * 64, d0 = blockIdx.y * 64, h = blockIdx.z;
  int tid = threadIdx.x;
  int li = tid >> 4;
  int lj = (tid & 15) * 4;
  #pragma unroll
  for (int p = 0; p < 4; ++p) {
    int i = p * 16 + li;
    ushort4 v = *(const ushort4*)(vb + (size_t)(t0 + i) * DM + h * 128 + d0 + lj);
    tile[i][lj] = v.x; tile[i][lj + 1] = v.y; tile[i][lj + 2] = v.z; tile[i][lj + 3] = v.w;
  }
  __syncthreads();
  #pragma unroll
  for (int p = 0; p < 4; ++p) {
    int j = p * 16 + li;
    ushort4 wv;
    wv.x = tile[lj][j]; wv.y = tile[lj + 1][j]; wv.z = tile[lj + 2][j]; wv.w = tile[lj + 3][j];
    *(ushort4*)(vbT + (size_t)h * 128 * TSEQ + (size_t)(d0 + j) * TSEQ + t0 + lj) = wv;
  }
}

// ---------------- split-KV causal flash attention (swapped QK^T) ----------
__global__ __launch_bounds__(512, 2) void attn_split(const unsigned short* __restrict__ qb,
                                                     const unsigned short* __restrict__ kb,
                                                     const unsigned short* __restrict__ vbT,
                                                     float* __restrict__ O01,
                                                     float* __restrict__ O23,
                                                     float2* __restrict__ ml) {
  __shared__ __align__(16) char Ks[2][16384];
  __shared__ __align__(16) char Vs[2][16384];

  int bi = blockIdx.x;
  int qblk = 7 - (bi >> 6);
  int h = (bi >> 2) & 15;
  int s = bi & 3;
  int len = qblk + 1;
  int st0 = s * len, st1 = st0 + len;

  int tid = threadIdx.x, w = tid >> 6, lane = tid & 63;
  int l15 = lane & 15, l4 = lane >> 4;
  int qr0 = qblk * 256 + w * 32;
  int xorK = (l15 & 7) << 4;
  int srcA = ((((l4 << 1)) & 3) * 16 + l15) << 2;
  int srcB = ((((l4 << 1) + 1) & 3) * 16 + l15) << 2;
  bool hi4 = (l4 >> 1) != 0;

  bf16x8 q_frag[2][4];
  #pragma unroll
  for (int qt = 0; qt < 2; ++qt) {
    const unsigned short* qrow = qb + (size_t)(qr0 + qt * 16 + l15) * DM + h * 128 + l4 * 8;
    #pragma unroll
    for (int kk = 0; kk < 4; ++kk) q_frag[qt][kk] = *(const bf16x8*)(qrow + kk * 32);
  }

  const char* kbase = (const char*)kb + (size_t)h * 256;
  const char* vbase = (const char*)vbT + (size_t)h * 128 * TSEQ * 2;

  f32x4 acc_o[2][8] = {};
  float mrow[2] = {-1e30f, -1e30f};
  float lrow[2] = {0.f, 0.f};
  const float scale = 0.08838834764831845f;

  auto stage = [&](int st, int bsel) {
    const char* kb1 = kbase + (size_t)st * 64 * 4096;
    const char* vb1 = vbase + (size_t)st * 64 * 2;
    #pragma unroll
    for (int it = 0; it < 2; ++it) {
      int L = (it * 512 + tid) * 16;
      int row = L >> 8, b = L & 255;
      const char* src = kb1 + (size_t)row * 4096 + (b ^ ((row & 7) << 4));
      __builtin_amdgcn_global_load_lds((gas_cvp)src, (las_vp)(&Ks[bsel][0] + L), 16, 0, 0);
    }
    #pragma unroll
    for (int it = 0; it < 2; ++it) {
      int L = (it * 512 + tid) * 16;
      int row = L >> 7, b = L & 127;
      const char* src = vb1 + (size_t)row * (TSEQ * 2) + (b ^ ((row & 7) << 4));
      __builtin_amdgcn_global_load_lds((gas_cvp)src, (las_vp)(&Vs[bsel][0] + L), 16, 0, 0);
    }
  };

  stage(st0, 0);
  int buf = 0;

  for (int st = st0; st < st1; ++st) {
    asm volatile("s_waitcnt vmcnt(0) lgkmcnt(0)" ::: "memory");
    __builtin_amdgcn_s_barrier();
    __builtin_amdgcn_sched_barrier(0);
    if (st + 1 < st1) stage(st + 1, buf ^ 1);

    f32x4 acc_s[2][4] = {};
    __builtin_amdgcn_s_setprio(1);
    #pragma unroll
    for (int j = 0; j < 4; ++j) {
      const char* kr = &Ks[buf][0] + (j * 16 + l15) * 256;
      #pragma unroll
      for (int kk = 0; kk < 4; ++kk) {
        bf16x8 kf = *(const bf16x8*)(kr + ((l4 * 16 + kk * 64) ^ xorK));
        acc_s[0][j] = __builtin_amdgcn_mfma_f32_16x16x32_bf16(kf, q_frag[0][kk], acc_s[0][j], 0, 0, 0);
        acc_s[1][j] = __builtin_amdgcn_mfma_f32_16x16x32_bf16(kf, q_frag[1][kk], acc_s[1][j], 0, 0, 0);
      }
    }
    __builtin_amdgcn_s_setprio(0);

    int kv0 = st * 64;
    bool needmask = (kv0 + 63) > qr0;
    u32x4v pf[2][2];

    #pragma unroll
    for (int qt = 0; qt < 2; ++qt) {
      int qg = qr0 + qt * 16 + l15;
      float sv[4][4];
      float pmax = -1e30f;
      if (needmask) {
        #pragma unroll
        for (int j = 0; j < 4; ++j)
          #pragma unroll
          for (int r = 0; r < 4; ++r) {
            float v = acc_s[qt][j][r] * scale;
            if ((kv0 + j * 16 + l4 * 4 + r) > qg) v = -1e30f;
            sv[j][r] = v;
            pmax = fmaxf(pmax, v);
          }
      } else {
        #pragma unroll
        for (int j = 0; j < 4; ++j)
          #pragma unroll
          for (int r = 0; r < 4; ++r) {
            float v = acc_s[qt][j][r] * scale;
            sv[j][r] = v;
            pmax = fmaxf(pmax, v);
          }
      }
      pmax = fmaxf(pmax, __shfl_xor(pmax, 16, 64));
      pmax = fmaxf(pmax, __shfl_xor(pmax, 32, 64));

      if (!__all(pmax - mrow[qt] <= 8.0f)) {
        float mn = fmaxf(mrow[qt], pmax);
        float f = __expf(mrow[qt] - mn);
        mrow[qt] = mn;
        lrow[qt] *= f;
        #pragma unroll
        for (int n = 0; n < 8; ++n) acc_o[qt][n] *= f;
      }
      float mn = mrow[qt];

      float psum = 0.f;
      unsigned pk[4][2];
      #pragma unroll
      for (int j = 0; j < 4; ++j)
        #pragma unroll
        for (int rr = 0; rr < 2; ++rr) {
          float p0 = __expf(sv[j][2 * rr] - mn);
          float p1 = __expf(sv[j][2 * rr + 1] - mn);
          psum += p0 + p1;
          unsigned pkw;
          asm("v_cvt_pk_bf16_f32 %0, %1, %2" : "=v"(pkw) : "v"(p0), "v"(p1));
          pk[j][rr] = pkw;
        }
      psum += __shfl_xor(psum, 16, 64);
      psum += __shfl_xor(psum, 32, 64);
      lrow[qt] += psum;

      #pragma unroll
      for (int kk = 0; kk < 2; ++kk) {
        u32x4v pw;
        #pragma unroll
        for (int w2 = 0; w2 < 4; ++w2) {
          int rr = w2 & 1;
          int src = (w2 < 2) ? srcA : srcB;
          unsigned c0 = (unsigned)__builtin_amdgcn_ds_bpermute(src, (int)pk[2 * kk][rr]);
          unsigned c1 = (unsigned)__builtin_amdgcn_ds_bpermute(src, (int)pk[2 * kk + 1][rr]);
          pw[w2] = hi4 ? c1 : c0;
        }
        pf[qt][kk] = pw;
      }
    }

    __builtin_amdgcn_s_setprio(1);
    #pragma unroll
    for (int kk = 0; kk < 2; ++kk) {
      bf16x8 pb0 = __builtin_bit_cast(bf16x8, pf[0][kk]);
      bf16x8 pb1 = __builtin_bit_cast(bf16x8, pf[1][kk]);
      #pragma unroll
      for (int n = 0; n < 8; ++n) {
        bf16x8 vf = *(const bf16x8*)(&Vs[buf][0] + (n * 16 + l15) * 128 + ((kk * 64 + l4 * 16) ^ xorK));
        acc_o[0][n] = __builtin_amdgcn_mfma_f32_16x16x32_bf16(vf, pb0, acc_o[0][n], 0, 0, 0);
        acc_o[1][n] = __builtin_amdgcn_mfma_f32_16x16x32_bf16(vf, pb1, acc_o[1][n], 0, 0, 0);
      }
    }
    __builtin_amdgcn_s_setprio(0);
    buf ^= 1;
  }

  float* Op = (s < 2 ? O01 + (size_t)s * (TSEQ * DM)
                     : O23 + (size_t)(s - 2) * (TSEQ * DM));
  #pragma unroll
  for (int qt = 0; qt < 2; ++qt) {
    int q = qr0 + qt * 16 + l15;
    #pragma unroll
    for (int n = 0; n < 8; ++n)
      *(f32x4*)(Op + (size_t)q * DM + h * 128 + n * 16 + l4 * 4) = acc_o[qt][n];
    if (l4 == 0)
      ml[(size_t)s * (TSEQ * NHEAD) + (size_t)q * NHEAD + h] = make_float2(mrow[qt], lrow[qt]);
  }
}

// ---------------- combine 4 split-KV partials -> bf16 y ---------------------
__global__ __launch_bounds__(256) void attn_combine(const float* __restrict__ O01,
                                                    const float* __restrict__ O23,
                                                    const float2* __restrict__ ml,
                                                    unsigned short* __restrict__ yb) {
  const int TN = TSEQ * NHEAD;
  int idx = blockIdx.x * 256 + threadIdx.x;
  int rowid = idx >> 5;
  float2 m0 = ml[rowid];
  float2 m1 = ml[TN + rowid];
  float2 m2 = ml[2 * TN + rowid];
  float2 m3 = ml[3 * TN + rowid];
  float m = fmaxf(fmaxf(m0.x, m1.x), fmaxf(m2.x, m3.x));
  float a0 = __expf(m0.x - m), a1 = __expf(m1.x - m);
  float a2 = __expf(m2.x - m), a3 = __expf(m3.x - m);
  float inv = 1.0f / (a0 * m0.y + a1 * m1.y + a2 * m2.y + a3 * m3.y);
  float4 o0 = ((const float4*)O01)[idx];
  float4 o1 = ((const float4*)(O01 + (size_t)TSEQ * DM))[idx];
  float4 o2 = ((const float4*)O23)[idx];
  float4 o3 = ((const float4*)(O23 + (size_t)TSEQ * DM))[idx];
  ushort4 r;
  r.x = f2bf((a0 * o0.x + a1 * o1.x + a2 * o2.x + a3 * o3.x) * inv);
  r.y = f2bf((a0 * o0.y + a1 * o1.y + a2 * o2.y + a3 * o3.y) * inv);
  r.z = f2bf((a0 * o0.z + a1 * o1.z + a2 * o2.z + a3 * o3.z) * inv);
  r.w = f2bf((a0 * o0.w + a1 * o1.w + a2 * o2.w + a3 * o3.w) * inv);
  *(ushort4*)(yb + (size_t)idx * 4) = r;
}

// ---------------------------------------------------------------------------
extern "C" void kernel_launch(void* const* d_in, const int* in_sizes, int n_in,
                              void* d_out, int out_size, void* d_ws, size_t ws_size,
                              hipStream_t stream) {
  const float* x   = (const float*)d_in[0];
  const float* vi  = (const float*)d_in[1];
  const float* wq  = (const float*)d_in[2];
  const float* wk  = (const float*)d_in[3];
  const float* wv  = (const float*)d_in[4];
  const float* wp  = (const float*)d_in[5];
  const float* lam = (const float*)d_in[6];

  const size_t MB = 1024 * 1024;
  const int NEL = DM * TSEQ;
  const int N8  = NEL / 8;
  char* ws = (char*)d_ws;
  unsigned short* xb    = (unsigned short*)(ws);
  unsigned short* wqkvb = (unsigned short*)(ws + 8  * MB);
  unsigned short* wpb   = (unsigned short*)(ws + 32 * MB);
  float*          qkv32 = (float*)(ws + 40 * MB);
  float*          O01   = (float*)(ws);
  float*          O23   = (float*)(ws + 40 * MB);
  float2*         mlbuf = (float2*)(ws + 72 * MB);
  unsigned short* qb2   = (unsigned short*)(ws + 88 * MB);
  unsigned short* kb2   = (unsigned short*)(ws + 96 * MB);
  unsigned short* vb    = (unsigned short*)(ws + 104 * MB);
  unsigned short* vbT   = (unsigned short*)(ws + 112 * MB);
  unsigned short* yb    = (unsigned short*)(ws + 120 * MB);

  cvt5<<<5 * N8 / 256, 256, 0, stream>>>(x, wq, wk, wv, wp, xb, wqkvb, wpb);

  gemm_qkv<<<256, 512, 0, stream>>>(xb, wqkvb, qkv32);

  qkv_post<<<(TSEQ * NHEAD) / 4, 256, 0, stream>>>(qkv32, vi, lam, qb2, kb2, vb);

  transpose_v<<<dim3(TSEQ / 64, 2, NHEAD), 256, 0, stream>>>(vb, vbT);

  attn_split<<<512, 512, 0, stream>>>(qb2, kb2, vbT, O01, O23, mlbuf);
  attn_combine<<<(TSEQ * DM / 4) / 256, 256, 0, stream>>>(O01, O23, mlbuf, yb);

  gemm_proj<<<256, 512, 0, stream>>>(yb, wpb, (float*)d_out);
}

// Round 13
// 162.119 us; speedup vs baseline: 1.0608x; 1.0586x over previous
//
#include <hip/hip_runtime.h>

#define TSEQ 2048
#define DM   2048
#define NHEAD 16

typedef __bf16 bf16x8 __attribute__((ext_vector_type(8)));
typedef float  f32x4  __attribute__((ext_vector_type(4)));
typedef unsigned short ushort8v __attribute__((ext_vector_type(8)));
typedef unsigned int u32x4v __attribute__((ext_vector_type(4)));
typedef const __attribute__((address_space(1))) void* gas_cvp;
typedef __attribute__((address_space(3))) void* las_vp;

__device__ __forceinline__ unsigned short f2bf(float f) {
  unsigned int u = __builtin_bit_cast(unsigned int, f);
  u += 0x7FFFu + ((u >> 16) & 1u);
  return (unsigned short)(u >> 16);
}
__device__ __forceinline__ float bf2f(unsigned short u) {
  return __builtin_bit_cast(float, (unsigned int)u << 16);
}

// ---------------- fused fp32 -> bf16 conversion (5 tensors, 1 launch) ------
__global__ __launch_bounds__(256) void cvt5(const float* __restrict__ x,
                                            const float* __restrict__ wq,
                                            const float* __restrict__ wk,
                                            const float* __restrict__ wv,
                                            const float* __restrict__ wp,
                                            unsigned short* __restrict__ xb,
                                            unsigned short* __restrict__ wqkvb,
                                            unsigned short* __restrict__ wpb) {
  const int NEL = DM * TSEQ;
  int gid = blockIdx.x * 256 + threadIdx.x;
  int seg = gid >> 19;
  int i = gid & ((1 << 19) - 1);
  const float* src;
  unsigned short* dst;
  switch (seg) {
    case 0: src = x;  dst = xb;                      break;
    case 1: src = wq; dst = wqkvb;                   break;
    case 2: src = wk; dst = wqkvb + (size_t)NEL;     break;
    case 3: src = wv; dst = wqkvb + (size_t)2 * NEL; break;
    default: src = wp; dst = wpb;                    break;
  }
  const float4* p = (const float4*)src + (size_t)i * 2;
  float4 a = p[0], b = p[1];
  ushort8v o;
  o[0] = f2bf(a.x); o[1] = f2bf(a.y); o[2] = f2bf(a.z); o[3] = f2bf(a.w);
  o[4] = f2bf(b.x); o[5] = f2bf(b.y); o[6] = f2bf(b.z); o[7] = f2bf(b.w);
  *((ushort8v*)dst + i) = o;
}

// ---------------- QKV GEMM: C[2048][6144] = A x B^T, bf16 out ---------------
// BM=256 BN=192, grid 256 = 1 block/CU. 512 threads, 8 waves (4M x 2N).
// Counted-vmcnt: stage A(4)/B(3); vmcnt(3)->bar->readA->stageA(t+1)->
// vmcnt(4)->bar->readB->stageB(t+1)->MFMA.
__global__ __launch_bounds__(512, 2) void gemm_qkv(const unsigned short* __restrict__ A,
                                                   const unsigned short* __restrict__ B,
                                                   unsigned short* __restrict__ C) {
  constexpr int TB = (256 + 192) * 128;   // 57344 B per buffer
  __shared__ char lds[2 * TB];

  int orig = blockIdx.x;
  int swz = (orig & 7) * 32 + (orig >> 3);
  int bx = swz & 31, by = swz >> 5;
  int tileM = by * 256, tileN = bx * 192;

  int tid = threadIdx.x, w = tid >> 6, lane = tid & 63;
  int l15 = lane & 15, l4 = lane >> 4;
  int wm = w >> 1, wn = w & 1;
  int xorsw = (l15 & 7) << 4;
  int srow = tid >> 3, scolb = (tid & 7) * 16;

  const char* Ag = (const char*)A;
  const char* Bg = (const char*)B;

  f32x4 acc[4][6] = {};

  auto stageA = [&](int kt, int bsel) {
    char* dst0 = lds + bsel * TB + srow * 128 + scolb;
    #pragma unroll
    for (int i = 0; i < 4; ++i) {
      int row = i * 64 + srow;
      const char* src = Ag + (size_t)(tileM + row) * 4096
                        + kt * 128 + (scolb ^ ((row & 7) << 4));
      __builtin_amdgcn_global_load_lds((gas_cvp)src, (las_vp)(dst0 + i * 8192), 16, 0, 0);
    }
  };
  auto stageB = [&](int kt, int bsel) {
    char* dst0 = lds + bsel * TB + 32768 + srow * 128 + scolb;
    #pragma unroll
    for (int i = 0; i < 3; ++i) {
      int row = i * 64 + srow;
      const char* src = Bg + (size_t)(tileN + row) * 4096
                        + kt * 128 + (scolb ^ ((row & 7) << 4));
      __builtin_amdgcn_global_load_lds((gas_cvp)src, (las_vp)(dst0 + i * 8192), 16, 0, 0);
    }
  };

  stageA(0, 0);
  stageB(0, 0);
  #pragma unroll 2
  for (int t = 0; t < 32; ++t) {
    int buf = t & 1;
    const char* Lb = lds + buf * TB;
    bool pf = (t + 1 < 32);

    asm volatile("s_waitcnt vmcnt(3)" ::: "memory");
    __builtin_amdgcn_s_barrier();
    asm volatile("" ::: "memory");

    bf16x8 a[4][2], b[6][2];
    #pragma unroll
    for (int mf = 0; mf < 4; ++mf)
      #pragma unroll
      for (int kk = 0; kk < 2; ++kk)
        a[mf][kk] = *(const bf16x8*)(Lb + (wm * 64 + mf * 16 + l15) * 128 + ((kk * 64 + l4 * 16) ^ xorsw));
    if (pf) stageA(t + 1, buf ^ 1);

    if (pf) { asm volatile("s_waitcnt vmcnt(4)" ::: "memory"); }
    else    { asm volatile("s_waitcnt vmcnt(0)" ::: "memory"); }
    __builtin_amdgcn_s_barrier();
    asm volatile("" ::: "memory");

    #pragma unroll
    for (int nf = 0; nf < 6; ++nf)
      #pragma unroll
      for (int kk = 0; kk < 2; ++kk)
        b[nf][kk] = *(const bf16x8*)(Lb + 32768 + (wn * 96 + nf * 16 + l15) * 128 + ((kk * 64 + l4 * 16) ^ xorsw));
    if (pf) stageB(t + 1, buf ^ 1);

    __builtin_amdgcn_s_setprio(1);
    #pragma unroll
    for (int kk = 0; kk < 2; ++kk)
      #pragma unroll
      for (int mf = 0; mf < 4; ++mf)
        #pragma unroll
        for (int nf = 0; nf < 6; ++nf)
          acc[mf][nf] = __builtin_amdgcn_mfma_f32_16x16x32_bf16(a[mf][kk], b[nf][kk], acc[mf][nf], 0, 0, 0);
    __builtin_amdgcn_s_setprio(0);
  }

  #pragma unroll
  for (int mf = 0; mf < 4; ++mf) {
    int r0 = tileM + wm * 64 + mf * 16 + l4 * 4;
    #pragma unroll
    for (int nf = 0; nf < 6; ++nf) {
      int c0 = tileN + wn * 96 + nf * 16 + l15;
      #pragma unroll
      for (int j = 0; j < 4; ++j)
        C[(size_t)(r0 + j) * 6144 + c0] = f2bf(acc[mf][nf][j]);
    }
  }
}

// ---------------- proj GEMM: C[2048][2048] = A x B^T -------------------------
__global__ __launch_bounds__(512, 2) void gemm_proj(const unsigned short* __restrict__ A,
                                                    const unsigned short* __restrict__ B,
                                                    float* __restrict__ C) {
  constexpr int TB = 256 * 128;
  __shared__ char lds[3 * TB];

  int orig = blockIdx.x;
  int swz = (orig & 7) * 32 + (orig >> 3);
  int bx = swz & 15, by = swz >> 4;
  int tileM = by * 128, tileN = bx * 128;

  int tid = threadIdx.x, w = tid >> 6, lane = tid & 63;
  int l15 = lane & 15, l4 = lane >> 4;
  int wm = w >> 2, wn = (w >> 1) & 1, ks = w & 1;
  int xorsw = (l15 & 7) << 4;
  int srow = tid >> 3, scolb = (tid & 7) * 16;
  int kb = ks * 64;

  const char* Ag = (const char*)A;
  const char* Bg = (const char*)B;

  f32x4 acc[4][4] = {};

  auto stage = [&](int kt, int bsel) {
    char* dst0 = lds + bsel * TB + srow * 128 + scolb;
    #pragma unroll
    for (int i = 0; i < 4; ++i) {
      int row = i * 64 + srow;
      const char* src = (row < 128 ? Ag + (size_t)(tileM + row) * 4096
                                   : Bg + (size_t)(tileN + row - 128) * 4096)
                        + kt * 128 + (scolb ^ ((row & 7) << 4));
      __builtin_amdgcn_global_load_lds((gas_cvp)src, (las_vp)(dst0 + i * 8192), 16, 0, 0);
    }
  };

  stage(0, 0);
  stage(1, 1);
  #pragma unroll 3
  for (int t = 0; t < 32; ++t) {
    int buf = t % 3;
    if (t + 1 < 32) { asm volatile("s_waitcnt vmcnt(4)" ::: "memory"); }
    else            { asm volatile("s_waitcnt vmcnt(0)" ::: "memory"); }
    __builtin_amdgcn_s_barrier();
    __builtin_amdgcn_sched_barrier(0);
    if (t + 2 < 32) stage(t + 2, (t + 2) % 3);

    const char* Lb = lds + buf * TB;
    bf16x8 a[4], b[4];
    #pragma unroll
    for (int mf = 0; mf < 4; ++mf)
      a[mf] = *(const bf16x8*)(Lb + (wm * 64 + mf * 16 + l15) * 128 + ((kb + l4 * 16) ^ xorsw));
    #pragma unroll
    for (int nf = 0; nf < 4; ++nf)
      b[nf] = *(const bf16x8*)(Lb + (128 + wn * 64 + nf * 16 + l15) * 128 + ((kb + l4 * 16) ^ xorsw));
    #pragma unroll
    for (int mf = 0; mf < 4; ++mf)
      #pragma unroll
      for (int nf = 0; nf < 4; ++nf)
        acc[mf][nf] = __builtin_amdgcn_mfma_f32_16x16x32_bf16(a[mf], b[nf], acc[mf][nf], 0, 0, 0);
  }

  __syncthreads();
  int pair = w >> 1;
  if (ks == 1) {
    #pragma unroll
    for (int mf = 0; mf < 4; ++mf)
      #pragma unroll
      for (int nf = 0; nf < 4; ++nf)
        *(f32x4*)(lds + pair * 16384 + ((mf * 4 + nf) * 64 + lane) * 16) = acc[mf][nf];
  }
  __syncthreads();
  if (ks == 0) {
    #pragma unroll
    for (int mf = 0; mf < 4; ++mf) {
      int r0 = tileM + wm * 64 + mf * 16 + l4 * 4;
      #pragma unroll
      for (int nf = 0; nf < 4; ++nf) {
        f32x4 o = acc[mf][nf] + *(const f32x4*)(lds + pair * 16384 + ((mf * 4 + nf) * 64 + lane) * 16);
        int c0 = tileN + wn * 64 + nf * 16 + l15;
        #pragma unroll
        for (int j = 0; j < 4; ++j)
          C[(size_t)(r0 + j) * 2048 + c0] = o[j];
      }
    }
  }
}

// ---------------- v-mix + RMSNorm + RoPE (one wave per (t,h), bf16 in) -----
__global__ __launch_bounds__(256) void qkv_post(const unsigned short* __restrict__ qkv,
                                                const float* __restrict__ vi,
                                                const float* __restrict__ lam,
                                                unsigned short* __restrict__ qb,
                                                unsigned short* __restrict__ kb,
                                                unsigned short* __restrict__ vb) {
  int wid = blockIdx.x * 4 + (threadIdx.x >> 6);
  int lane = threadIdx.x & 63;
  int t = wid >> 4, h = wid & 15;
  const unsigned short* base = qkv + (size_t)t * (3 * DM) + h * 128;
  float l0 = lam[0], l1 = lam[1];

  float invf = exp2f((float)lane * -0.20762050593046014f);
  float ang = (float)t * invf;
  float sn, cs;
  sincosf(ang, &sn, &cs);

  size_t ob = (size_t)t * DM + h * 128;
  {
    float a = bf2f(base[lane]), b = bf2f(base[lane + 64]);
    float ss = a * a + b * b;
    #pragma unroll
    for (int m = 1; m < 64; m <<= 1) ss += __shfl_xor(ss, m, 64);
    float sc = rsqrtf(ss * (1.0f / 128.0f) + 1.1920929e-07f);
    a *= sc; b *= sc;
    qb[ob + lane]      = f2bf(a * cs + b * sn);
    qb[ob + 64 + lane] = f2bf(b * cs - a * sn);
  }
  {
    float a = bf2f(base[2048 + lane]), b = bf2f(base[2048 + 64 + lane]);
    float ss = a * a + b * b;
    #pragma unroll
    for (int m = 1; m < 64; m <<= 1) ss += __shfl_xor(ss, m, 64);
    float sc = rsqrtf(ss * (1.0f / 128.0f) + 1.1920929e-07f);
    a *= sc; b *= sc;
    kb[ob + lane]      = f2bf(a * cs + b * sn);
    kb[ob + 64 + lane] = f2bf(b * cs - a * sn);
  }
  {
    const float* vib = vi + (size_t)t * DM + h * 128;
    vb[ob + lane]      = f2bf(l0 * bf2f(base[4096 + lane])      + l1 * vib[lane]);
    vb[ob + 64 + lane] = f2bf(l0 * bf2f(base[4096 + 64 + lane]) + l1 * vib[lane + 64]);
  }
}

// ---------------- V transpose: vb[t][h*128+d] -> vbT[h][d][t] -------------
__global__ __launch_bounds__(256) void transpose_v(const unsigned short* __restrict__ vb,
                                                   unsigned short* __restrict__ vbT) {
  __shared__ __align__(16) unsigned short tile[64][68];
  int t0 = blockIdx.x * 64, d0 = blockIdx.y * 64, h = blockIdx.z;
  int tid = threadIdx.x;
  int li = tid >> 4;
  int lj = (tid & 15) * 4;
  #pragma unroll
  for (int p = 0; p < 4; ++p) {
    int i = p * 16 + li;
    ushort4 v = *(const ushort4*)(vb + (size_t)(t0 + i) * DM + h * 128 + d0 + lj);
    tile[i][lj] = v.x; tile[i][lj + 1] = v.y; tile[i][lj + 2] = v.z; tile[i][lj + 3] = v.w;
  }
  __syncthreads();
  #pragma unroll
  for (int p = 0; p < 4; ++p) {
    int j = p * 16 + li;
    ushort4 wv;
    wv.x = tile[lj][j]; wv.y = tile[lj + 1][j]; wv.z = tile[lj + 2][j]; wv.w = tile[lj + 3][j];
    *(ushort4*)(vbT + (size_t)h * 128 * TSEQ + (size_t)(d0 + j) * TSEQ + t0 + lj) = wv;
  }
}

// ---------------- split-KV causal flash attention (swapped QK^T) ----------
// bf16 O-partials (halves split-KV HBM tax).
__global__ __launch_bounds__(512, 2) void attn_split(const unsigned short* __restrict__ qb,
                                                     const unsigned short* __restrict__ kb,
                                                     const unsigned short* __restrict__ vbT,
                                                     unsigned short* __restrict__ O01,
                                                     unsigned short* __restrict__ O23,
                                                     float2* __restrict__ ml) {
  __shared__ __align__(16) char Ks[2][16384];
  __shared__ __align__(16) char Vs[2][16384];

  int bi = blockIdx.x;
  int qblk = 7 - (bi >> 6);
  int h = (bi >> 2) & 15;
  int s = bi & 3;
  int len = qblk + 1;
  int st0 = s * len, st1 = st0 + len;

  int tid = threadIdx.x, w = tid >> 6, lane = tid & 63;
  int l15 = lane & 15, l4 = lane >> 4;
  int qr0 = qblk * 256 + w * 32;
  int xorK = (l15 & 7) << 4;
  int srcA = ((((l4 << 1)) & 3) * 16 + l15) << 2;
  int srcB = ((((l4 << 1) + 1) & 3) * 16 + l15) << 2;
  bool hi4 = (l4 >> 1) != 0;

  bf16x8 q_frag[2][4];
  #pragma unroll
  for (int qt = 0; qt < 2; ++qt) {
    const unsigned short* qrow = qb + (size_t)(qr0 + qt * 16 + l15) * DM + h * 128 + l4 * 8;
    #pragma unroll
    for (int kk = 0; kk < 4; ++kk) q_frag[qt][kk] = *(const bf16x8*)(qrow + kk * 32);
  }

  const char* kbase = (const char*)kb + (size_t)h * 256;
  const char* vbase = (const char*)vbT + (size_t)h * 128 * TSEQ * 2;

  f32x4 acc_o[2][8] = {};
  float mrow[2] = {-1e30f, -1e30f};
  float lrow[2] = {0.f, 0.f};
  const float scale = 0.08838834764831845f;

  auto stage = [&](int st, int bsel) {
    const char* kb1 = kbase + (size_t)st * 64 * 4096;
    const char* vb1 = vbase + (size_t)st * 64 * 2;
    #pragma unroll
    for (int it = 0; it < 2; ++it) {
      int L = (it * 512 + tid) * 16;
      int row = L >> 8, b = L & 255;
      const char* src = kb1 + (size_t)row * 4096 + (b ^ ((row & 7) << 4));
      __builtin_amdgcn_global_load_lds((gas_cvp)src, (las_vp)(&Ks[bsel][0] + L), 16, 0, 0);
    }
    #pragma unroll
    for (int it = 0; it < 2; ++it) {
      int L = (it * 512 + tid) * 16;
      int row = L >> 7, b = L & 127;
      const char* src = vb1 + (size_t)row * (TSEQ * 2) + (b ^ ((row & 7) << 4));
      __builtin_amdgcn_global_load_lds((gas_cvp)src, (las_vp)(&Vs[bsel][0] + L), 16, 0, 0);
    }
  };

  stage(st0, 0);
  int buf = 0;

  for (int st = st0; st < st1; ++st) {
    asm volatile("s_waitcnt vmcnt(0) lgkmcnt(0)" ::: "memory");
    __builtin_amdgcn_s_barrier();
    __builtin_amdgcn_sched_barrier(0);
    if (st + 1 < st1) stage(st + 1, buf ^ 1);

    f32x4 acc_s[2][4] = {};
    __builtin_amdgcn_s_setprio(1);
    #pragma unroll
    for (int j = 0; j < 4; ++j) {
      const char* kr = &Ks[buf][0] + (j * 16 + l15) * 256;
      #pragma unroll
      for (int kk = 0; kk < 4; ++kk) {
        bf16x8 kf = *(const bf16x8*)(kr + ((l4 * 16 + kk * 64) ^ xorK));
        acc_s[0][j] = __builtin_amdgcn_mfma_f32_16x16x32_bf16(kf, q_frag[0][kk], acc_s[0][j], 0, 0, 0);
        acc_s[1][j] = __builtin_amdgcn_mfma_f32_16x16x32_bf16(kf, q_frag[1][kk], acc_s[1][j], 0, 0, 0);
      }
    }
    __builtin_amdgcn_s_setprio(0);

    int kv0 = st * 64;
    bool needmask = (kv0 + 63) > qr0;
    u32x4v pf[2][2];

    #pragma unroll
    for (int qt = 0; qt < 2; ++qt) {
      int qg = qr0 + qt * 16 + l15;
      float sv[4][4];
      float pmax = -1e30f;
      if (needmask) {
        #pragma unroll
        for (int j = 0; j < 4; ++j)
          #pragma unroll
          for (int r = 0; r < 4; ++r) {
            float v = acc_s[qt][j][r] * scale;
            if ((kv0 + j * 16 + l4 * 4 + r) > qg) v = -1e30f;
            sv[j][r] = v;
            pmax = fmaxf(pmax, v);
          }
      } else {
        #pragma unroll
        for (int j = 0; j < 4; ++j)
          #pragma unroll
          for (int r = 0; r < 4; ++r) {
            float v = acc_s[qt][j][r] * scale;
            sv[j][r] = v;
            pmax = fmaxf(pmax, v);
          }
      }
      pmax = fmaxf(pmax, __shfl_xor(pmax, 16, 64));
      pmax = fmaxf(pmax, __shfl_xor(pmax, 32, 64));

      if (!__all(pmax - mrow[qt] <= 8.0f)) {
        float mn = fmaxf(mrow[qt], pmax);
        float f = __expf(mrow[qt] - mn);
        mrow[qt] = mn;
        lrow[qt] *= f;
        #pragma unroll
        for (int n = 0; n < 8; ++n) acc_o[qt][n] *= f;
      }
      float mn = mrow[qt];

      float psum = 0.f;
      unsigned pk[4][2];
      #pragma unroll
      for (int j = 0; j < 4; ++j)
        #pragma unroll
        for (int rr = 0; rr < 2; ++rr) {
          float p0 = __expf(sv[j][2 * rr] - mn);
          float p1 = __expf(sv[j][2 * rr + 1] - mn);
          psum += p0 + p1;
          unsigned pkw;
          asm("v_cvt_pk_bf16_f32 %0, %1, %2" : "=v"(pkw) : "v"(p0), "v"(p1));
          pk[j][rr] = pkw;
        }
      psum += __shfl_xor(psum, 16, 64);
      psum += __shfl_xor(psum, 32, 64);
      lrow[qt] += psum;

      #pragma unroll
      for (int kk = 0; kk < 2; ++kk) {
        u32x4v pw;
        #pragma unroll
        for (int w2 = 0; w2 < 4; ++w2) {
          int rr = w2 & 1;
          int src = (w2 < 2) ? srcA : srcB;
          unsigned c0 = (unsigned)__builtin_amdgcn_ds_bpermute(src, (int)pk[2 * kk][rr]);
          unsigned c1 = (unsigned)__builtin_amdgcn_ds_bpermute(src, (int)pk[2 * kk + 1][rr]);
          pw[w2] = hi4 ? c1 : c0;
        }
        pf[qt][kk] = pw;
      }
    }

    __builtin_amdgcn_s_setprio(1);
    #pragma unroll
    for (int kk = 0; kk < 2; ++kk) {
      bf16x8 pb0 = __builtin_bit_cast(bf16x8, pf[0][kk]);
      bf16x8 pb1 = __builtin_bit_cast(bf16x8, pf[1][kk]);
      #pragma unroll
      for (int n = 0; n < 8; ++n) {
        bf16x8 vf = *(const bf16x8*)(&Vs[buf][0] + (n * 16 + l15) * 128 + ((kk * 64 + l4 * 16) ^ xorK));
        acc_o[0][n] = __builtin_amdgcn_mfma_f32_16x16x32_bf16(vf, pb0, acc_o[0][n], 0, 0, 0);
        acc_o[1][n] = __builtin_amdgcn_mfma_f32_16x16x32_bf16(vf, pb1, acc_o[1][n], 0, 0, 0);
      }
    }
    __builtin_amdgcn_s_setprio(0);
    buf ^= 1;
  }

  unsigned short* Op = (s < 2 ? O01 + (size_t)s * (TSEQ * DM)
                              : O23 + (size_t)(s - 2) * (TSEQ * DM));
  #pragma unroll
  for (int qt = 0; qt < 2; ++qt) {
    int q = qr0 + qt * 16 + l15;
    #pragma unroll
    for (int n = 0; n < 8; ++n) {
      ushort4 st4;
      st4.x = f2bf(acc_o[qt][n][0]);
      st4.y = f2bf(acc_o[qt][n][1]);
      st4.z = f2bf(acc_o[qt][n][2]);
      st4.w = f2bf(acc_o[qt][n][3]);
      *(ushort4*)(Op + (size_t)q * DM + h * 128 + n * 16 + l4 * 4) = st4;
    }
    if (l4 == 0)
      ml[(size_t)s * (TSEQ * NHEAD) + (size_t)q * NHEAD + h] = make_float2(mrow[qt], lrow[qt]);
  }
}

// ---------------- combine 4 split-KV partials (bf16) -> bf16 y --------------
__global__ __launch_bounds__(256) void attn_combine(const unsigned short* __restrict__ O01,
                                                    const unsigned short* __restrict__ O23,
                                                    const float2* __restrict__ ml,
                                                    unsigned short* __restrict__ yb) {
  const int TN = TSEQ * NHEAD;
  int idx = blockIdx.x * 256 + threadIdx.x;   // ushort4 index
  int rowid = idx >> 5;
  float2 m0 = ml[rowid];
  float2 m1 = ml[TN + rowid];
  float2 m2 = ml[2 * TN + rowid];
  float2 m3 = ml[3 * TN + rowid];
  float m = fmaxf(fmaxf(m0.x, m1.x), fmaxf(m2.x, m3.x));
  float a0 = __expf(m0.x - m), a1 = __expf(m1.x - m);
  float a2 = __expf(m2.x - m), a3 = __expf(m3.x - m);
  float inv = 1.0f / (a0 * m0.y + a1 * m1.y + a2 * m2.y + a3 * m3.y);
  ushort4 o0 = ((const ushort4*)O01)[idx];
  ushort4 o1 = ((const ushort4*)(O01 + (size_t)TSEQ * DM))[idx];
  ushort4 o2 = ((const ushort4*)O23)[idx];
  ushort4 o3 = ((const ushort4*)(O23 + (size_t)TSEQ * DM))[idx];
  ushort4 r;
  r.x = f2bf((a0 * bf2f(o0.x) + a1 * bf2f(o1.x) + a2 * bf2f(o2.x) + a3 * bf2f(o3.x)) * inv);
  r.y = f2bf((a0 * bf2f(o0.y) + a1 * bf2f(o1.y) + a2 * bf2f(o2.y) + a3 * bf2f(o3.y)) * inv);
  r.z = f2bf((a0 * bf2f(o0.z) + a1 * bf2f(o1.z) + a2 * bf2f(o2.z) + a3 * bf2f(o3.z)) * inv);
  r.w = f2bf((a0 * bf2f(o0.w) + a1 * bf2f(o1.w) + a2 * bf2f(o2.w) + a3 * bf2f(o3.w)) * inv);
  *(ushort4*)(yb + (size_t)idx * 4) = r;
}

// ---------------------------------------------------------------------------
extern "C" void kernel_launch(void* const* d_in, const int* in_sizes, int n_in,
                              void* d_out, int out_size, void* d_ws, size_t ws_size,
                              hipStream_t stream) {
  const float* x   = (const float*)d_in[0];
  const float* vi  = (const float*)d_in[1];
  const float* wq  = (const float*)d_in[2];
  const float* wk  = (const float*)d_in[3];
  const float* wv  = (const float*)d_in[4];
  const float* wp  = (const float*)d_in[5];
  const float* lam = (const float*)d_in[6];

  const size_t MB = 1024 * 1024;
  const int NEL = DM * TSEQ;
  const int N8  = NEL / 8;
  char* ws = (char*)d_ws;
  unsigned short* xb    = (unsigned short*)(ws);            // dead after gemm_qkv
  unsigned short* wqkvb = (unsigned short*)(ws + 8  * MB);   // dead after gemm_qkv
  unsigned short* wpb   = (unsigned short*)(ws + 32 * MB);   // live until gemm_proj
  unsigned short* qkvb  = (unsigned short*)(ws + 40 * MB);   // bf16 [T][6144], 24MB, dead after qkv_post
  unsigned short* O01   = (unsigned short*)(ws);             // bf16 2x8MB, reuses xb/wqkvb
  unsigned short* O23   = (unsigned short*)(ws + 64 * MB);   // bf16 2x8MB, after qkvb
  float2*         mlbuf = (float2*)(ws + 84 * MB);           // 1MB
  unsigned short* qb2   = (unsigned short*)(ws + 88 * MB);
  unsigned short* kb2   = (unsigned short*)(ws + 96 * MB);
  unsigned short* vb    = (unsigned short*)(ws + 104 * MB);
  unsigned short* vbT   = (unsigned short*)(ws + 112 * MB);
  unsigned short* yb    = (unsigned short*)(ws + 120 * MB);

  cvt5<<<5 * N8 / 256, 256, 0, stream>>>(x, wq, wk, wv, wp, xb, wqkvb, wpb);

  gemm_qkv<<<256, 512, 0, stream>>>(xb, wqkvb, qkvb);

  qkv_post<<<(TSEQ * NHEAD) / 4, 256, 0, stream>>>(qkvb, vi, lam, qb2, kb2, vb);

  transpose_v<<<dim3(TSEQ / 64, 2, NHEAD), 256, 0, stream>>>(vb, vbT);

  attn_split<<<512, 512, 0, stream>>>(qb2, kb2, vbT, O01, O23, mlbuf);
  attn_combine<<<(TSEQ * DM / 4) / 256, 256, 0, stream>>>(O01, O23, mlbuf, yb);

  gemm_proj<<<256, 512, 0, stream>>>(yb, wpb, (float*)d_out);
}